// Round 2
// baseline (688.243 us; speedup 1.0000x reference)
//
#include <hip/hip_runtime.h>
#include <math.h>

#define N_ROWS 32768
#define M_CODES 2048
#define D_DIM 512
#define MARGIN 1.2e-3f
#define CAND_CAP 32

// d_out flat offsets (floats), reference return order
#define OUT_QST       0
#define OUT_COMMIT    16777216
#define OUT_CODEBOOK  16777217
#define OUT_ORTHO     16777218
#define OUT_INDICES   16777219
#define OUT_NEWEMB    16809987
#define OUT_NEWCOUNT  17858563
#define OUT_NEWW      17860611

// ---------------- workspace layout (float offsets) ----------------
// zeroed region: [0, WS_ZERO_FLOATS)
#define WS_COUNTS     0            // 2048 floats
#define WS_CURSOR     2048         // 2048 ints
#define WS_SSE        4096         // 1
#define WS_ORTHO      4097         // 1 (+6 pad)
#define WS_CANDCNT    4104         // 32768 ints
#define WS_ZERO_FLOATS 36872
#define WS_E2         36872        // 2048
#define WS_X2         38920        // 32768
#define WS_IDX        71688        // 32768 (int)
#define WS_NCN        104456       // 2048
#define WS_SEL        106504       // 128 (int)
#define WS_VALID      106632       // 128
#define WS_NVALID     106760       // 1 (+7 pad)
#define WS_NORMED     106768       // 65536
#define WS_NORMEDT    172304       // 65536
#define WS_OFFS       237840       // 2048 ints (+8 pad)
#define WS_ORDER      239896       // 32768 ints
#define WS_CANDC      272664       // 32768*32 ints
#define WS_CANDD      1321240      // 32768*32 floats
#define WS_XH         2369816      // 32768*512 shorts (8388608 float slots)
#define WS_EH         10758424     // 2048*512 shorts (524288 float slots)
#define WS_TOTAL_FLOATS 11282712

typedef __attribute__((ext_vector_type(8))) short short8v;
typedef __attribute__((ext_vector_type(4))) float f32x4;

__device__ __forceinline__ unsigned short f2bf(float f) {
    unsigned u = __float_as_uint(f);
    unsigned r = (u + 0x7fffu + ((u >> 16) & 1u)) >> 16;
    return (unsigned short)r;
}

// ---------------- prep: e2/x2 + bf16 (single, round-to-nearest) ----------------
__global__ __launch_bounds__(256) void prep_kernel(const float* __restrict__ emb,
                                                   const float* __restrict__ x,
                                                   float* __restrict__ e2,
                                                   float* __restrict__ x2,
                                                   unsigned short* __restrict__ xh,
                                                   unsigned short* __restrict__ eh) {
    int row  = blockIdx.x * 4 + (threadIdx.x >> 6);
    int lane = threadIdx.x & 63;
    bool is_e = row < M_CODES;
    const float* src = is_e ? (emb + (size_t)row * D_DIM)
                            : (x + (size_t)(row - M_CODES) * D_DIM);
    unsigned short* dh = is_e ? (eh + (size_t)row * D_DIM)
                              : (xh + (size_t)(row - M_CODES) * D_DIM);
    float4 a = *(const float4*)(src + lane * 4);
    float4 b = *(const float4*)(src + 256 + lane * 4);
    float s = a.x*a.x + a.y*a.y + a.z*a.z + a.w*a.w
            + b.x*b.x + b.y*b.y + b.z*b.z + b.w*b.w;
#pragma unroll
    for (int o = 32; o > 0; o >>= 1) s += __shfl_xor(s, o, 64);

    ushort4 h0, h1;
    h0.x = f2bf(a.x); h0.y = f2bf(a.y); h0.z = f2bf(a.z); h0.w = f2bf(a.w);
    h1.x = f2bf(b.x); h1.y = f2bf(b.y); h1.z = f2bf(b.z); h1.w = f2bf(b.w);
    *(ushort4*)(dh + lane * 4)       = h0;
    *(ushort4*)(dh + 256 + lane * 4) = h1;

    if (lane == 0) {
        if (is_e) e2[row] = s;
        else      x2[row - M_CODES] = s;
    }
}

// ---------------- sq only (fallback path) ----------------
__global__ __launch_bounds__(256) void sq_kernel(const float* __restrict__ emb,
                                                 const float* __restrict__ x,
                                                 float* __restrict__ e2,
                                                 float* __restrict__ x2) {
    int row  = blockIdx.x * 4 + (threadIdx.x >> 6);
    int lane = threadIdx.x & 63;
    const float* src = (row < M_CODES) ? (emb + (size_t)row * D_DIM)
                                       : (x + (size_t)(row - M_CODES) * D_DIM);
    float4 a = *(const float4*)(src + lane * 4);
    float4 b = *(const float4*)(src + 256 + lane * 4);
    float s = a.x*a.x + a.y*a.y + a.z*a.z + a.w*a.w
            + b.x*b.x + b.y*b.y + b.z*b.z + b.w*b.w;
#pragma unroll
    for (int o = 32; o > 0; o >>= 1) s += __shfl_xor(s, o, 64);
    if (lane == 0) {
        if (row < M_CODES) e2[row] = s;
        else               x2[row - M_CODES] = s;
    }
}

// ---------------- barrier-free reg-A / L2-B approx distances ----------------
// eh (2 MB) is L2-resident per XCD; A rows live in 128 VGPRs per wave.
// Each wave: 32 rows x 1024 codes, chunks of 64 codes, zero LDS, zero
// __syncthreads (raw s_barrier only paces waves for L1 reuse).
// Candidate emission vs running per-row prefix-min: superset of the
// {d <= global_min + MARGIN} set (proof: when the argmin's chunk is
// processed, rmin == its d, so it and all margin-mates always append).
__global__ __launch_bounds__(256) void approx2_kernel(const unsigned short* __restrict__ xh,
                                                      const unsigned short* __restrict__ eh,
                                                      const float* __restrict__ e2g,
                                                      int* __restrict__ candcnt,
                                                      int* __restrict__ candC,
                                                      float* __restrict__ candD) {
    const int t  = threadIdx.x;
    const int w  = t >> 6;
    const int l  = t & 63;
    const int ml = l & 15;
    const int q  = l >> 4;

    // bid&1 -> code half, so each XCD's L2 caches only one 1 MB half
    const int row0      = (blockIdx.x >> 1) * 128 + w * 32;  // wave's 32 rows
    const int code_base = (blockIdx.x & 1) * 1024;

    // A fragments in registers: lane holds rows (row0+mi*16+ml), k = kk*32+q*8..+8
    short8v af[2][16];
#pragma unroll
    for (int mi = 0; mi < 2; ++mi) {
        const unsigned short* ar = xh + (size_t)(row0 + mi * 16 + ml) * D_DIM + q * 8;
#pragma unroll
        for (int kk = 0; kk < 16; ++kk)
            af[mi][kk] = *(const short8v*)(ar + kk * 32);
    }

    float rmin[2][4];
#pragma unroll
    for (int mi = 0; mi < 2; ++mi)
#pragma unroll
        for (int r = 0; r < 4; ++r) rmin[mi][r] = 3.0e38f;

    for (int ch = 0; ch < 16; ++ch) {
        // convoy the block's waves for L1 reuse; no inter-wave data deps,
        // so a raw barrier (no waitcnt drain) is correct.
        __builtin_amdgcn_s_barrier();

        const int code0 = code_base + ch * 64;

        f32x4 acc[2][4];
#pragma unroll
        for (int mi = 0; mi < 2; ++mi)
#pragma unroll
            for (int ni = 0; ni < 4; ++ni) acc[mi][ni] = (f32x4)0.f;

        const unsigned short* br = eh + (size_t)(code0 + ml) * D_DIM + q * 8;
#pragma unroll
        for (int kk = 0; kk < 16; ++kk) {
            short8v b0 = *(const short8v*)(br + (size_t)(0 * 16) * D_DIM + kk * 32);
            short8v b1 = *(const short8v*)(br + (size_t)(1 * 16) * D_DIM + kk * 32);
            short8v b2 = *(const short8v*)(br + (size_t)(2 * 16) * D_DIM + kk * 32);
            short8v b3 = *(const short8v*)(br + (size_t)(3 * 16) * D_DIM + kk * 32);
            acc[0][0] = __builtin_amdgcn_mfma_f32_16x16x32_bf16(af[0][kk], b0, acc[0][0], 0, 0, 0);
            acc[1][0] = __builtin_amdgcn_mfma_f32_16x16x32_bf16(af[1][kk], b0, acc[1][0], 0, 0, 0);
            acc[0][1] = __builtin_amdgcn_mfma_f32_16x16x32_bf16(af[0][kk], b1, acc[0][1], 0, 0, 0);
            acc[1][1] = __builtin_amdgcn_mfma_f32_16x16x32_bf16(af[1][kk], b1, acc[1][1], 0, 0, 0);
            acc[0][2] = __builtin_amdgcn_mfma_f32_16x16x32_bf16(af[0][kk], b2, acc[0][2], 0, 0, 0);
            acc[1][2] = __builtin_amdgcn_mfma_f32_16x16x32_bf16(af[1][kk], b2, acc[1][2], 0, 0, 0);
            acc[0][3] = __builtin_amdgcn_mfma_f32_16x16x32_bf16(af[0][kk], b3, acc[0][3], 0, 0, 0);
            acc[1][3] = __builtin_amdgcn_mfma_f32_16x16x32_bf16(af[1][kk], b3, acc[1][3], 0, 0, 0);
        }

        // epilogue: d = e2 - 2*acc; chunk-min per row; prefix-min; appends
        float e2v[4];
#pragma unroll
        for (int ni = 0; ni < 4; ++ni) e2v[ni] = e2g[code0 + ni * 16 + ml];

#pragma unroll
        for (int mi = 0; mi < 2; ++mi)
#pragma unroll
            for (int r = 0; r < 4; ++r) {
                float v = fminf(fminf(e2v[0] - 2.0f * acc[mi][0][r],
                                      e2v[1] - 2.0f * acc[mi][1][r]),
                                fminf(e2v[2] - 2.0f * acc[mi][2][r],
                                      e2v[3] - 2.0f * acc[mi][3][r]));
#pragma unroll
                for (int o = 1; o < 16; o <<= 1) v = fminf(v, __shfl_xor(v, o, 64));
                rmin[mi][r] = fminf(rmin[mi][r], v);
            }

#pragma unroll
        for (int mi = 0; mi < 2; ++mi)
#pragma unroll
            for (int r = 0; r < 4; ++r) {
                const float rm = rmin[mi][r] + MARGIN;
                const int row_g = row0 + mi * 16 + q * 4 + r;
#pragma unroll
                for (int ni = 0; ni < 4; ++ni) {
                    float dd = e2v[ni] - 2.0f * acc[mi][ni][r];
                    if (dd <= rm) {
                        int pos = atomicAdd(&candcnt[row_g], 1);
                        if (pos < CAND_CAP) {
                            candC[row_g * CAND_CAP + pos] = code0 + ni * 16 + ml;
                            candD[row_g * CAND_CAP + pos] = dd;
                        }
                    }
                }
            }
    }
}

// ---------------- exact re-rank + histogram ----------------
__global__ __launch_bounds__(256) void rerank_kernel(const float* __restrict__ x,
                                                     const float* __restrict__ emb,
                                                     const float* __restrict__ e2,
                                                     const float* __restrict__ x2,
                                                     const int* __restrict__ candcnt,
                                                     const int* __restrict__ candC,
                                                     const float* __restrict__ candD,
                                                     float* __restrict__ counts,
                                                     int* __restrict__ idx_out,
                                                     float* __restrict__ idxf_out) {
    const int w = threadIdx.x >> 6;
    const int lane = threadIdx.x & 63;
    const int row = blockIdx.x * 4 + w;

    int cnt = candcnt[row];
    int best_c;

    if (cnt > CAND_CAP) {
        // overflow safety net (rare): exact scan of all codes (lanes parallel over codes)
        const float x2r = x2[row];
        const float* xr = x + (size_t)row * D_DIM;
        float bd = 3.0e38f;
        int   bc = 0x7fffffff;
        for (int c = lane; c < M_CODES; c += 64) {
            const float* er = emb + (size_t)c * D_DIM;
            float dot = 0.f;
            for (int k = 0; k < D_DIM; ++k) dot = fmaf(xr[k], er[k], dot);
            float d = (x2r + e2[c]) - 2.0f * dot;
            if (d < bd || (d == bd && c < bc)) { bd = d; bc = c; }
        }
#pragma unroll
        for (int o = 32; o > 0; o >>= 1) {
            float od = __shfl_xor(bd, o, 64);
            int   oc = __shfl_xor(bc, o, 64);
            if (od < bd || (od == bd && oc < bc)) { bd = od; bc = oc; }
        }
        best_c = bc;
    } else {
        float d = 3.0e38f;
        int   c = 0x7fffffff;
        if (lane < cnt) {
            d = candD[row * CAND_CAP + lane];
            c = candC[row * CAND_CAP + lane];
        }
        float dmin = d;
#pragma unroll
        for (int o = 32; o > 0; o >>= 1) dmin = fminf(dmin, __shfl_xor(dmin, o, 64));

        bool surv = (lane < cnt) && (d <= dmin + MARGIN);
        unsigned long long mask = __ballot(surv);

        if (__popcll(mask) == 1) {
            int src = __ffsll((long long)mask) - 1;
            best_c = __shfl(c, src, 64);
        } else {
            // lane-parallel exact rerank of survivors
            const float x2r = x2[row];
            const float* xr = x + (size_t)row * D_DIM;
            float4 xa = *(const float4*)(xr + lane * 8);
            float4 xb = *(const float4*)(xr + lane * 8 + 4);
            float bd = 3.0e38f;
            int   bc = 0x7fffffff;
            unsigned long long m = mask;
            while (m) {
                int src = __ffsll((long long)m) - 1;
                m &= m - 1;
                int cs = __shfl(c, src, 64);
                const float* er = emb + (size_t)cs * D_DIM;
                float4 ea = *(const float4*)(er + lane * 8);
                float4 eb = *(const float4*)(er + lane * 8 + 4);
                float dot = xa.x*ea.x + xa.y*ea.y + xa.z*ea.z + xa.w*ea.w
                          + xb.x*eb.x + xb.y*eb.y + xb.z*eb.z + xb.w*eb.w;
#pragma unroll
                for (int o = 32; o > 0; o >>= 1) dot += __shfl_xor(dot, o, 64);
                float t1 = x2r + e2[cs];
                float dex = t1 - 2.0f * dot;
                if (dex < bd || (dex == bd && cs < bc)) { bd = dex; bc = cs; }
            }
            best_c = bc;
        }
    }
    if (lane == 0) {
        idx_out[row] = best_c;
        idxf_out[row] = (float)best_c;
        atomicAdd(&counts[best_c], 1.0f);
    }
}

// ---------------- fallback fp32 argmin (round-1 kernel) ----------------
__global__ __launch_bounds__(256) void argmin_kernel(const float* __restrict__ x,
                                                     const float* __restrict__ emb,
                                                     const float* __restrict__ e2,
                                                     const float* __restrict__ x2,
                                                     int* __restrict__ idx_out,
                                                     float* __restrict__ idxf_out) {
    __shared__ float As[64][36];
    __shared__ float Bs[32][68];
    __shared__ float e2s[64];
    __shared__ float redD[64][17];
    __shared__ int   redI[64][17];

    const int t  = threadIdx.x;
    const int tx = t & 15;
    const int ty = t >> 4;
    const int row0 = blockIdx.x * 64;

    float rmin[4];
    int   ridx[4];
#pragma unroll
    for (int r = 0; r < 4; ++r) { rmin[r] = 3.0e38f; ridx[r] = 0; }

    float x2r[4];
#pragma unroll
    for (int r = 0; r < 4; ++r) x2r[r] = x2[row0 + ty * 4 + r];

    const int lr = t >> 3;
    const int lc = t & 7;

    for (int m0 = 0; m0 < M_CODES; m0 += 64) {
        __syncthreads();
        if (t < 64) e2s[t] = e2[m0 + t];

        float acc[4][4];
#pragma unroll
        for (int r = 0; r < 4; ++r)
#pragma unroll
            for (int c = 0; c < 4; ++c) acc[r][c] = 0.f;

        for (int k0 = 0; k0 < D_DIM; k0 += 32) {
            __syncthreads();
#pragma unroll
            for (int p = 0; p < 2; ++p) {
                int r = p * 32 + lr;
                float4 v = *(const float4*)(x + (size_t)(row0 + r) * D_DIM + k0 + lc * 4);
                *(float4*)(&As[r][lc * 4]) = v;
            }
#pragma unroll
            for (int p = 0; p < 2; ++p) {
                int r = p * 32 + lr;
                float4 v = *(const float4*)(emb + (size_t)(m0 + r) * D_DIM + k0 + lc * 4);
                Bs[lc * 4 + 0][r] = v.x;
                Bs[lc * 4 + 1][r] = v.y;
                Bs[lc * 4 + 2][r] = v.z;
                Bs[lc * 4 + 3][r] = v.w;
            }
            __syncthreads();

#pragma unroll
            for (int kk = 0; kk < 32; kk += 4) {
                float av[4][4], bv[4][4];
#pragma unroll
                for (int r = 0; r < 4; ++r) {
                    float4 a4 = *(const float4*)(&As[ty * 4 + r][kk]);
                    av[r][0] = a4.x; av[r][1] = a4.y; av[r][2] = a4.z; av[r][3] = a4.w;
                }
#pragma unroll
                for (int j = 0; j < 4; ++j) {
                    float4 b4 = *(const float4*)(&Bs[kk + j][tx * 4]);
                    bv[j][0] = b4.x; bv[j][1] = b4.y; bv[j][2] = b4.z; bv[j][3] = b4.w;
                }
#pragma unroll
                for (int j = 0; j < 4; ++j)
#pragma unroll
                    for (int r = 0; r < 4; ++r)
#pragma unroll
                        for (int c = 0; c < 4; ++c)
                            acc[r][c] += av[r][j] * bv[j][c];
            }
        }

#pragma unroll
        for (int c = 0; c < 4; ++c) {
            int mm = tx * 4 + c;
            int m  = m0 + mm;
            float e2v = e2s[mm];
#pragma unroll
            for (int r = 0; r < 4; ++r) {
                float t1 = x2r[r] + e2v;
                float dd  = t1 - 2.0f * acc[r][c];
                if (dd < rmin[r]) { rmin[r] = dd; ridx[r] = m; }
            }
        }
    }

    __syncthreads();
#pragma unroll
    for (int r = 0; r < 4; ++r) {
        redD[ty * 4 + r][tx] = rmin[r];
        redI[ty * 4 + r][tx] = ridx[r];
    }
    __syncthreads();
    if (t < 64) {
        float best = redD[t][0];
        int   bi   = redI[t][0];
#pragma unroll
        for (int i = 1; i < 16; ++i) {
            float dd = redD[t][i];
            int   ii = redI[t][i];
            if (dd < best || (dd == best && ii < bi)) { best = dd; bi = ii; }
        }
        idx_out[row0 + t]  = bi;
        idxf_out[row0 + t] = (float)bi;
    }
}

// ---------------- histogram (fallback path only) ----------------
__global__ __launch_bounds__(256) void hist_kernel(const int* __restrict__ idx,
                                                   float* __restrict__ counts) {
    int r = blockIdx.x * 256 + threadIdx.x;
    atomicAdd(&counts[idx[r]], 1.0f);
}

// ---------------- quant_st + SSE (streaming, no atomic scatter) ----------------
__global__ __launch_bounds__(256) void qst_sse_kernel(const float* __restrict__ x,
                                                      const float* __restrict__ emb,
                                                      const int* __restrict__ idx,
                                                      float* __restrict__ sse,
                                                      float* __restrict__ qst) {
    const int w    = threadIdx.x >> 6;
    const int lane = threadIdx.x & 63;
    const int rowbase = blockIdx.x * 16 + w * 4;
    float loss = 0.f;
    for (int i = 0; i < 4; ++i) {
        const int row = rowbase + i;
        const int m   = idx[row];
#pragma unroll
        for (int j = 0; j < 2; ++j) {
            const int off = j * 256 + lane * 4;
            float4 xv = *(const float4*)(x + (size_t)row * D_DIM + off);
            float4 qv = *(const float4*)(emb + (size_t)m * D_DIM + off);
            float4 qs;
            qs.x = xv.x + (qv.x - xv.x);
            qs.y = xv.y + (qv.y - xv.y);
            qs.z = xv.z + (qv.z - xv.z);
            qs.w = xv.w + (qv.w - xv.w);
            *(float4*)(qst + (size_t)row * D_DIM + off) = qs;
            float dx;
            dx = xv.x - qv.x; loss += dx * dx;
            dx = xv.y - qv.y; loss += dx * dx;
            dx = xv.z - qv.z; loss += dx * dx;
            dx = xv.w - qv.w; loss += dx * dx;
        }
    }
#pragma unroll
    for (int o = 32; o > 0; o >>= 1) loss += __shfl_xor(loss, o, 64);
    if (lane == 0) atomicAdd(sse, loss);
}

// ---------------- EMA count + Laplace normalize ----------------
__global__ __launch_bounds__(256) void f1_kernel(const float* __restrict__ ema_count,
                                                 const float* __restrict__ counts,
                                                 float* __restrict__ out_newcount,
                                                 float* __restrict__ nc_ws) {
    __shared__ float red[256];
    int t = threadIdx.x;
    float raw[8];
    float part = 0.f;
#pragma unroll
    for (int i = 0; i < 8; ++i) {
        int m = t * 8 + i;
        raw[i] = 0.999f * ema_count[m] + 0.001f * counts[m];
        part += raw[i];
    }
    red[t] = part;
    __syncthreads();
    for (int s = 128; s > 0; s >>= 1) {
        if (t < s) red[t] += red[t + s];
        __syncthreads();
    }
    float n = red[0];
    float denom = n + (float)M_CODES * 1e-5f;
#pragma unroll
    for (int i = 0; i < 8; ++i) {
        int m = t * 8 + i;
        float v = (raw[i] + 1e-5f) / denom * n;
        out_newcount[m] = v;
        nc_ws[m] = v;
    }
}

// ---------------- exclusive prefix of counts -> offs ----------------
__global__ __launch_bounds__(256) void scan_kernel(const float* __restrict__ counts,
                                                   int* __restrict__ offs) {
    __shared__ int pre[257];
    int t = threadIdx.x;
    int c[8];
    int s = 0;
#pragma unroll
    for (int i = 0; i < 8; ++i) { c[i] = (int)counts[t * 8 + i]; s += c[i]; }
    pre[t] = s;
    __syncthreads();
    if (t == 0) {
        int run = 0;
        for (int i = 0; i < 256; ++i) { int v = pre[i]; pre[i] = run; run += v; }
        pre[256] = run;
    }
    __syncthreads();
    int base = pre[t];
#pragma unroll
    for (int i = 0; i < 8; ++i) { offs[t * 8 + i] = base; base += c[i]; }
}

// ---------------- fill per-code row lists ----------------
__global__ __launch_bounds__(256) void fill_kernel(const int* __restrict__ idx,
                                                   const int* __restrict__ offs,
                                                   int* __restrict__ cursor,
                                                   int* __restrict__ order) {
    int r = blockIdx.x * 256 + threadIdx.x;
    int m = idx[r];
    int pos = atomicAdd(&cursor[m], 1);
    order[offs[m] + pos] = r;
}

// ---------------- gather-reduce dw + EMA weight + new embedding ----------------
__global__ __launch_bounds__(256) void gather_nw_kernel(const float* __restrict__ x,
                                                        const float* __restrict__ ema_weight,
                                                        const float* __restrict__ ncn,
                                                        const float* __restrict__ counts,
                                                        const int* __restrict__ offs,
                                                        const int* __restrict__ order,
                                                        float* __restrict__ out_ne,
                                                        float* __restrict__ out_nw) {
    const int m = blockIdx.x;
    const int t = threadIdx.x;
    const int beg = offs[m];
    const int end = beg + (int)counts[m];
    float ax = 0.f, ay = 0.f;
    for (int j = beg; j < end; ++j) {
        int r = order[j];
        float2 v = *(const float2*)(x + (size_t)r * D_DIM + t * 2);
        ax += v.x; ay += v.y;
    }
    size_t i = (size_t)m * D_DIM + t * 2;
    float2 wv = *(const float2*)(ema_weight + i);
    float  c  = ncn[m];
    float2 nw, ne;
    nw.x = 0.999f * wv.x + 0.001f * ax; ne.x = nw.x / c;
    nw.y = 0.999f * wv.y + 0.001f * ay; ne.y = nw.y / c;
    *(float2*)(out_nw + i) = nw;
    *(float2*)(out_ne + i) = ne;
}

// ---------------- stable compaction (used-first), normalize rows ----------------
__global__ __launch_bounds__(256) void g1_kernel(const float* __restrict__ counts,
                                                 const float* __restrict__ new_emb,
                                                 int* __restrict__ sel,
                                                 float* __restrict__ valid,
                                                 float* __restrict__ n_valid,
                                                 float* __restrict__ normed,
                                                 float* __restrict__ normedT) {
    __shared__ int pre[257];
    int t = threadIdx.x;
    int u = 0;
#pragma unroll
    for (int i = 0; i < 8; ++i) u += (counts[t * 8 + i] > 0.f) ? 1 : 0;
    pre[t] = u;
    __syncthreads();
    if (t == 0) {
        int run = 0;
        for (int i = 0; i < 256; ++i) { int c = pre[i]; pre[i] = run; run += c; }
        pre[256] = run;
    }
    __syncthreads();
    int U = pre[256];
    int base = pre[t];
    int run = 0;
    for (int i = 0; i < 8; ++i) {
        int m = t * 8 + i;
        bool used = counts[m] > 0.f;
        int ur = base + run;
        if (used) {
            if (ur < 128) sel[ur] = m;
            run++;
        } else {
            int pos = U + (m - ur);
            if (pos < 128) sel[pos] = m;
        }
    }
    __syncthreads();
    if (t < 128) valid[t] = (counts[sel[t]] > 0.f) ? 1.f : 0.f;
    __syncthreads();
    if (t == 0) {
        float s = 0.f;
        for (int i = 0; i < 128; ++i) s += valid[i];
        *n_valid = s;
    }
    int w = t >> 6, lane = t & 63;
    for (int r = w; r < 128; r += 4) {
        int sm = sel[r];
        const float* src = new_emb + (size_t)sm * D_DIM;
        float4 a = *(const float4*)(src + lane * 4);
        float4 b = *(const float4*)(src + 256 + lane * 4);
        float s = a.x*a.x + a.y*a.y + a.z*a.z + a.w*a.w
                + b.x*b.x + b.y*b.y + b.z*b.z + b.w*b.w;
#pragma unroll
        for (int o = 32; o > 0; o >>= 1) s += __shfl_xor(s, o, 64);
        float norm = fmaxf(sqrtf(s), 1e-12f);
        float vv = valid[r];
        float4 na, nb;
        na.x = a.x / norm * vv; na.y = a.y / norm * vv;
        na.z = a.z / norm * vv; na.w = a.w / norm * vv;
        nb.x = b.x / norm * vv; nb.y = b.y / norm * vv;
        nb.z = b.z / norm * vv; nb.w = b.w / norm * vv;
        *(float4*)(normed + (size_t)r * D_DIM + lane * 4) = na;
        *(float4*)(normed + (size_t)r * D_DIM + 256 + lane * 4) = nb;
        normedT[(lane * 4 + 0) * 128 + r] = na.x;
        normedT[(lane * 4 + 1) * 128 + r] = na.y;
        normedT[(lane * 4 + 2) * 128 + r] = na.z;
        normedT[(lane * 4 + 3) * 128 + r] = na.w;
        normedT[(256 + lane * 4 + 0) * 128 + r] = nb.x;
        normedT[(256 + lane * 4 + 1) * 128 + r] = nb.y;
        normedT[(256 + lane * 4 + 2) * 128 + r] = nb.z;
        normedT[(256 + lane * 4 + 3) * 128 + r] = nb.w;
    }
}

// ---------------- cosine-sim loss accumulation ----------------
__global__ __launch_bounds__(128) void g2_kernel(const float* __restrict__ normed,
                                                 const float* __restrict__ normedT,
                                                 const float* __restrict__ valid,
                                                 float* __restrict__ ortho_acc) {
    __shared__ float rowi[512];
    __shared__ float red[128];
    int i = blockIdx.x, t = threadIdx.x;
    *(float4*)(rowi + t * 4) = *(const float4*)(normed + (size_t)i * D_DIM + t * 4);
    __syncthreads();
    float dot = 0.f;
    for (int k = 0; k < D_DIM; ++k) dot += rowi[k] * normedT[k * 128 + t];
    float diag = (i == t) ? valid[i] : 0.f;
    float d = dot - diag;
    red[t] = d * d;
    __syncthreads();
    for (int s = 64; s > 0; s >>= 1) {
        if (t < s) red[t] += red[t + s];
        __syncthreads();
    }
    if (t == 0) atomicAdd(ortho_acc, red[0]);
}

// ---------------- final scalars ----------------
__global__ void g3_kernel(const float* __restrict__ sse,
                          const float* __restrict__ ortho_acc,
                          const float* __restrict__ n_valid,
                          float* __restrict__ out3) {
    if (threadIdx.x == 0 && blockIdx.x == 0) {
        float m = *sse / 16777216.f;
        out3[0] = 0.25f * m;
        out3[1] = m;
        float nv = *n_valid;
        out3[2] = *ortho_acc / (nv * nv) * 10.f;
    }
}

extern "C" void kernel_launch(void* const* d_in, const int* in_sizes, int n_in,
                              void* d_out, int out_size, void* d_ws, size_t ws_size,
                              hipStream_t stream) {
    const float* x          = (const float*)d_in[0];
    const float* emb        = (const float*)d_in[1];
    const float* ema_count  = (const float*)d_in[2];
    const float* ema_weight = (const float*)d_in[3];
    float* out = (float*)d_out;
    float* ws  = (float*)d_ws;

    float* counts  = ws + WS_COUNTS;
    int*   cursor  = (int*)(ws + WS_CURSOR);
    float* sse     = ws + WS_SSE;
    float* ortho   = ws + WS_ORTHO;
    int*   candcnt = (int*)(ws + WS_CANDCNT);
    float* e2      = ws + WS_E2;
    float* x2      = ws + WS_X2;
    int*   idxws   = (int*)(ws + WS_IDX);
    float* ncn     = ws + WS_NCN;
    int*   sel     = (int*)(ws + WS_SEL);
    float* valid   = ws + WS_VALID;
    float* nvalid  = ws + WS_NVALID;
    float* normed  = ws + WS_NORMED;
    float* normedT = ws + WS_NORMEDT;
    int*   offs    = (int*)(ws + WS_OFFS);
    int*   order   = (int*)(ws + WS_ORDER);
    int*   candC   = (int*)(ws + WS_CANDC);
    float* candD   = ws + WS_CANDD;
    unsigned short* xh = (unsigned short*)(ws + WS_XH);
    unsigned short* eh = (unsigned short*)(ws + WS_EH);

    const bool big_ws = ws_size >= (size_t)WS_TOTAL_FLOATS * sizeof(float);

    hipMemsetAsync(ws, 0, (size_t)WS_ZERO_FLOATS * sizeof(float), stream);

    if (big_ws) {
        prep_kernel<<<(M_CODES + N_ROWS) / 4, 256, 0, stream>>>(emb, x, e2, x2, xh, eh);
        approx2_kernel<<<512, 256, 0, stream>>>(xh, eh, e2, candcnt, candC, candD);
        rerank_kernel<<<N_ROWS / 4, 256, 0, stream>>>(x, emb, e2, x2, candcnt, candC, candD,
                                                      counts, idxws, out + OUT_INDICES);
    } else {
        sq_kernel<<<(M_CODES + N_ROWS) / 4, 256, 0, stream>>>(emb, x, e2, x2);
        argmin_kernel<<<N_ROWS / 64, 256, 0, stream>>>(x, emb, e2, x2, idxws,
                                                       out + OUT_INDICES);
        hist_kernel<<<N_ROWS / 256, 256, 0, stream>>>(idxws, counts);
    }

    qst_sse_kernel<<<N_ROWS / 16, 256, 0, stream>>>(x, emb, idxws, sse, out + OUT_QST);

    f1_kernel<<<1, 256, 0, stream>>>(ema_count, counts, out + OUT_NEWCOUNT, ncn);

    scan_kernel<<<1, 256, 0, stream>>>(counts, offs);

    fill_kernel<<<N_ROWS / 256, 256, 0, stream>>>(idxws, offs, cursor, order);

    gather_nw_kernel<<<M_CODES, 256, 0, stream>>>(x, ema_weight, ncn, counts, offs, order,
                                                  out + OUT_NEWEMB, out + OUT_NEWW);

    g1_kernel<<<1, 256, 0, stream>>>(counts, out + OUT_NEWEMB, sel, valid, nvalid,
                                     normed, normedT);

    g2_kernel<<<128, 128, 0, stream>>>(normed, normedT, valid, ortho);

    g3_kernel<<<1, 64, 0, stream>>>(sse, ortho, nvalid, out + OUT_COMMIT);
}

// Round 3
// 651.115 us; speedup vs baseline: 1.0570x; 1.0570x over previous
//
#include <hip/hip_runtime.h>
#include <math.h>

#define N_ROWS 32768
#define M_CODES 2048
#define D_DIM 512
#define MARGIN 1.2e-3f
#define CAND_CAP 32

// d_out flat offsets (floats), reference return order
#define OUT_QST       0
#define OUT_COMMIT    16777216
#define OUT_CODEBOOK  16777217
#define OUT_ORTHO     16777218
#define OUT_INDICES   16777219
#define OUT_NEWEMB    16809987
#define OUT_NEWCOUNT  17858563
#define OUT_NEWW      17860611

// ---------------- workspace layout (float offsets) ----------------
// zeroed region: [0, WS_ZERO_FLOATS)
#define WS_COUNTS     0            // 2048 floats
#define WS_CURSOR     2048         // 2048 ints
#define WS_SSE        4096         // 1
#define WS_ORTHO      4097         // 1 (+6 pad)
#define WS_CANDCNT    4104         // 32768 ints
#define WS_ZERO_FLOATS 36872
#define WS_E2         36872        // 2048
#define WS_X2         38920        // 32768
#define WS_IDX        71688        // 32768 (int)
#define WS_NCN        104456       // 2048
#define WS_SEL        106504       // 128 (int)
#define WS_VALID      106632       // 128
#define WS_NVALID     106760       // 1 (+7 pad)
#define WS_NORMED     106768       // 65536
#define WS_NORMEDT    172304       // 65536
#define WS_OFFS       237840       // 2048 ints (+8 pad)
#define WS_ORDER      239896       // 32768 ints
#define WS_CANDC      272664       // 32768*32 ints
#define WS_CANDD      1321240      // 32768*32 floats
#define WS_XH         2369816      // 32768*512 shorts (8388608 float slots)
#define WS_EH         10758424     // 2048*512 shorts (524288 float slots)
#define WS_TOTAL_FLOATS 11282712

typedef __attribute__((ext_vector_type(8))) short short8v;
typedef __attribute__((ext_vector_type(4))) float f32x4;

__device__ __forceinline__ unsigned short f2bf(float f) {
    unsigned u = __float_as_uint(f);
    unsigned r = (u + 0x7fffu + ((u >> 16) & 1u)) >> 16;
    return (unsigned short)r;
}

#define GLOAD16(g, s) __builtin_amdgcn_global_load_lds( \
    (const __attribute__((address_space(1))) void*)(g), \
    (__attribute__((address_space(3))) void*)(s), 16, 0, 0)

// ---------------- prep: e2/x2 + bf16 (single, round-to-nearest) ----------------
__global__ __launch_bounds__(256) void prep_kernel(const float* __restrict__ emb,
                                                   const float* __restrict__ x,
                                                   float* __restrict__ e2,
                                                   float* __restrict__ x2,
                                                   unsigned short* __restrict__ xh,
                                                   unsigned short* __restrict__ eh) {
    int row  = blockIdx.x * 4 + (threadIdx.x >> 6);
    int lane = threadIdx.x & 63;
    bool is_e = row < M_CODES;
    const float* src = is_e ? (emb + (size_t)row * D_DIM)
                            : (x + (size_t)(row - M_CODES) * D_DIM);
    unsigned short* dh = is_e ? (eh + (size_t)row * D_DIM)
                              : (xh + (size_t)(row - M_CODES) * D_DIM);
    float4 a = *(const float4*)(src + lane * 4);
    float4 b = *(const float4*)(src + 256 + lane * 4);
    float s = a.x*a.x + a.y*a.y + a.z*a.z + a.w*a.w
            + b.x*b.x + b.y*b.y + b.z*b.z + b.w*b.w;
#pragma unroll
    for (int o = 32; o > 0; o >>= 1) s += __shfl_xor(s, o, 64);

    ushort4 h0, h1;
    h0.x = f2bf(a.x); h0.y = f2bf(a.y); h0.z = f2bf(a.z); h0.w = f2bf(a.w);
    h1.x = f2bf(b.x); h1.y = f2bf(b.y); h1.z = f2bf(b.z); h1.w = f2bf(b.w);
    *(ushort4*)(dh + lane * 4)       = h0;
    *(ushort4*)(dh + 256 + lane * 4) = h1;

    if (lane == 0) {
        if (is_e) e2[row] = s;
        else      x2[row - M_CODES] = s;
    }
}

// ---------------- sq only (fallback path) ----------------
__global__ __launch_bounds__(256) void sq_kernel(const float* __restrict__ emb,
                                                 const float* __restrict__ x,
                                                 float* __restrict__ e2,
                                                 float* __restrict__ x2) {
    int row  = blockIdx.x * 4 + (threadIdx.x >> 6);
    int lane = threadIdx.x & 63;
    const float* src = (row < M_CODES) ? (emb + (size_t)row * D_DIM)
                                       : (x + (size_t)(row - M_CODES) * D_DIM);
    float4 a = *(const float4*)(src + lane * 4);
    float4 b = *(const float4*)(src + 256 + lane * 4);
    float s = a.x*a.x + a.y*a.y + a.z*a.z + a.w*a.w
            + b.x*b.x + b.y*b.y + b.z*b.z + b.w*b.w;
#pragma unroll
    for (int o = 32; o > 0; o >>= 1) s += __shfl_xor(s, o, 64);
    if (lane == 0) {
        if (row < M_CODES) e2[row] = s;
        else               x2[row - M_CODES] = s;
    }
}

// ---------------- MFMA bf16 approx distances, 2-phase prefetch ----------------
// Block: 128 rows x 512 codes (4 ct-tiles of 128). Double-buffered LDS with
// 1-deep prefetch: STAGE(buf^1, next tile) -> compute(buf) -> barrier -> swap.
// Wave-private rows (wave w owns rows w*32..+32, all 128 codes of the ct), so
// the per-ct row-min is in-register + 4-step shfl (no LDS atomics, no extra
// barriers). Candidate emission vs per-row prefix-min across cts (superset of
// {d <= global_min + MARGIN}: at the argmin's tile, rmin == its d).
__global__ __launch_bounds__(256) void approx3_kernel(const unsigned short* __restrict__ xh,
                                                      const unsigned short* __restrict__ eh,
                                                      const float* __restrict__ e2g,
                                                      int* __restrict__ candcnt,
                                                      int* __restrict__ candC,
                                                      float* __restrict__ candD) {
    __shared__ short Ah[2][8192], Bh[2][8192];   // 2 x (128 rows x 64 bf16), dbuf

    const int t  = threadIdx.x;
    const int w  = t >> 6;
    const int l  = t & 63;
    const int ml = l & 15;
    const int q  = l >> 4;

    const int bid = blockIdx.x;
    const int row_tile = (bid >> 5) * 8 + (bid & 7);
    const int sub = (bid >> 3) & 3;
    const int row0 = row_tile * 128;
    const int code_base = sub * 512;
    const int wrow = row0 + w * 32;   // wave's private 32 rows

    // staging: round i=0..3 stages 32 rows x 128 B per matrix; lane l covers
    // row (i*32+w*8+(l>>3)), LDS piece (l&7) holds global piece (l&7)^(row&7)
    const int grow = l >> 3;
    const int pg8  = ((l & 7) ^ grow) * 8;

#define STAGE_AB(buf, ctv, k0v) do {                                              \
    _Pragma("unroll")                                                             \
    for (int i_ = 0; i_ < 4; ++i_) {                                              \
        int r_ = i_ * 32 + w * 8 + grow;                                          \
        GLOAD16(xh + (size_t)(row0 + r_) * D_DIM + (k0v) * 64 + pg8,              \
                &Ah[(buf)][i_ * 2048 + w * 512]);                                 \
        GLOAD16(eh + (size_t)(code_base + (ctv) * 128 + r_) * D_DIM               \
                   + (k0v) * 64 + pg8,                                            \
                &Bh[(buf)][i_ * 2048 + w * 512]);                                 \
    }                                                                             \
} while (0)

    float rmin[2][4];
#pragma unroll
    for (int mi = 0; mi < 2; ++mi)
#pragma unroll
        for (int r = 0; r < 4; ++r) rmin[mi][r] = 3.0e38f;

    // prologue: stage (ct=0, k0=0)
    STAGE_AB(0, 0, 0);
    __syncthreads();
    int cur = 0;

    for (int ct = 0; ct < 4; ++ct) {
        const int code0 = code_base + ct * 128;

        f32x4 acc[2][8];
#pragma unroll
        for (int mi = 0; mi < 2; ++mi)
#pragma unroll
            for (int ni = 0; ni < 8; ++ni) acc[mi][ni] = (f32x4)0.f;

        for (int k0 = 0; k0 < 8; ++k0) {
            // prefetch next tile into the other buffer
            if (k0 < 7)           STAGE_AB(cur ^ 1, ct, k0 + 1);
            else if (ct < 3)      STAGE_AB(cur ^ 1, ct + 1, 0);

            // compute on current buffer
            const short* Ab = &Ah[cur][0];
            const short* Bb = &Bh[cur][0];
#pragma unroll
            for (int kk = 0; kk < 64; kk += 32) {
                const int sw = ((((kk >> 3) + q)) ^ (ml & 7)) << 3;
                short8v a0 = *(const short8v*)(Ab + (w * 32 + ml) * 64 + sw);
                short8v a1 = *(const short8v*)(Ab + (w * 32 + 16 + ml) * 64 + sw);
#pragma unroll
                for (int ni = 0; ni < 8; ++ni) {
                    short8v b = *(const short8v*)(Bb + (ni * 16 + ml) * 64 + sw);
                    acc[0][ni] = __builtin_amdgcn_mfma_f32_16x16x32_bf16(a0, b, acc[0][ni], 0, 0, 0);
                    acc[1][ni] = __builtin_amdgcn_mfma_f32_16x16x32_bf16(a1, b, acc[1][ni], 0, 0, 0);
                }
            }

            if (k0 < 7) { __syncthreads(); cur ^= 1; }
        }

        // epilogue (register-only; overlaps the (ct+1,0) staging in flight)
        float e2v[8];
#pragma unroll
        for (int ni = 0; ni < 8; ++ni) e2v[ni] = e2g[code0 + ni * 16 + ml];

#pragma unroll
        for (int mi = 0; mi < 2; ++mi)
#pragma unroll
            for (int r = 0; r < 4; ++r) {
                float v = 3.0e38f;
#pragma unroll
                for (int ni = 0; ni < 8; ++ni)
                    v = fminf(v, e2v[ni] - 2.0f * acc[mi][ni][r]);
#pragma unroll
                for (int o = 1; o < 16; o <<= 1) v = fminf(v, __shfl_xor(v, o, 64));
                rmin[mi][r] = fminf(rmin[mi][r], v);
                const float rm = rmin[mi][r] + MARGIN;
                const int row_g = wrow + mi * 16 + q * 4 + r;
#pragma unroll
                for (int ni = 0; ni < 8; ++ni) {
                    float dd = e2v[ni] - 2.0f * acc[mi][ni][r];
                    if (dd <= rm) {
                        int pos = atomicAdd(&candcnt[row_g], 1);
                        if (pos < CAND_CAP) {
                            candC[row_g * CAND_CAP + pos] = code0 + ni * 16 + ml;
                            candD[row_g * CAND_CAP + pos] = dd;
                        }
                    }
                }
            }

        __syncthreads();   // (ct+1,0) staging complete; safe to swap
        cur ^= 1;
    }
#undef STAGE_AB
}

// ---------------- exact re-rank + histogram ----------------
__global__ __launch_bounds__(256) void rerank_kernel(const float* __restrict__ x,
                                                     const float* __restrict__ emb,
                                                     const float* __restrict__ e2,
                                                     const float* __restrict__ x2,
                                                     const int* __restrict__ candcnt,
                                                     const int* __restrict__ candC,
                                                     const float* __restrict__ candD,
                                                     float* __restrict__ counts,
                                                     int* __restrict__ idx_out,
                                                     float* __restrict__ idxf_out) {
    const int w = threadIdx.x >> 6;
    const int lane = threadIdx.x & 63;
    const int row = blockIdx.x * 4 + w;

    int cnt = candcnt[row];
    int best_c;

    if (cnt > CAND_CAP) {
        // overflow safety net (rare): exact scan of all codes (lanes parallel over codes)
        const float x2r = x2[row];
        const float* xr = x + (size_t)row * D_DIM;
        float bd = 3.0e38f;
        int   bc = 0x7fffffff;
        for (int c = lane; c < M_CODES; c += 64) {
            const float* er = emb + (size_t)c * D_DIM;
            float dot = 0.f;
            for (int k = 0; k < D_DIM; ++k) dot = fmaf(xr[k], er[k], dot);
            float d = (x2r + e2[c]) - 2.0f * dot;
            if (d < bd || (d == bd && c < bc)) { bd = d; bc = c; }
        }
#pragma unroll
        for (int o = 32; o > 0; o >>= 1) {
            float od = __shfl_xor(bd, o, 64);
            int   oc = __shfl_xor(bc, o, 64);
            if (od < bd || (od == bd && oc < bc)) { bd = od; bc = oc; }
        }
        best_c = bc;
    } else {
        float d = 3.0e38f;
        int   c = 0x7fffffff;
        if (lane < cnt) {
            d = candD[row * CAND_CAP + lane];
            c = candC[row * CAND_CAP + lane];
        }
        float dmin = d;
#pragma unroll
        for (int o = 32; o > 0; o >>= 1) dmin = fminf(dmin, __shfl_xor(dmin, o, 64));

        bool surv = (lane < cnt) && (d <= dmin + MARGIN);
        unsigned long long mask = __ballot(surv);

        if (__popcll(mask) == 1) {
            int src = __ffsll((long long)mask) - 1;
            best_c = __shfl(c, src, 64);
        } else {
            // lane-parallel exact rerank of survivors
            const float x2r = x2[row];
            const float* xr = x + (size_t)row * D_DIM;
            float4 xa = *(const float4*)(xr + lane * 8);
            float4 xb = *(const float4*)(xr + lane * 8 + 4);
            float bd = 3.0e38f;
            int   bc = 0x7fffffff;
            unsigned long long m = mask;
            while (m) {
                int src = __ffsll((long long)m) - 1;
                m &= m - 1;
                int cs = __shfl(c, src, 64);
                const float* er = emb + (size_t)cs * D_DIM;
                float4 ea = *(const float4*)(er + lane * 8);
                float4 eb = *(const float4*)(er + lane * 8 + 4);
                float dot = xa.x*ea.x + xa.y*ea.y + xa.z*ea.z + xa.w*ea.w
                          + xb.x*eb.x + xb.y*eb.y + xb.z*eb.z + xb.w*eb.w;
#pragma unroll
                for (int o = 32; o > 0; o >>= 1) dot += __shfl_xor(dot, o, 64);
                float t1 = x2r + e2[cs];
                float dex = t1 - 2.0f * dot;
                if (dex < bd || (dex == bd && cs < bc)) { bd = dex; bc = cs; }
            }
            best_c = bc;
        }
    }
    if (lane == 0) {
        idx_out[row] = best_c;
        idxf_out[row] = (float)best_c;
        atomicAdd(&counts[best_c], 1.0f);
    }
}

// ---------------- fallback fp32 argmin (round-1 kernel) ----------------
__global__ __launch_bounds__(256) void argmin_kernel(const float* __restrict__ x,
                                                     const float* __restrict__ emb,
                                                     const float* __restrict__ e2,
                                                     const float* __restrict__ x2,
                                                     int* __restrict__ idx_out,
                                                     float* __restrict__ idxf_out) {
    __shared__ float As[64][36];
    __shared__ float Bs[32][68];
    __shared__ float e2s[64];
    __shared__ float redD[64][17];
    __shared__ int   redI[64][17];

    const int t  = threadIdx.x;
    const int tx = t & 15;
    const int ty = t >> 4;
    const int row0 = blockIdx.x * 64;

    float rmin[4];
    int   ridx[4];
#pragma unroll
    for (int r = 0; r < 4; ++r) { rmin[r] = 3.0e38f; ridx[r] = 0; }

    float x2r[4];
#pragma unroll
    for (int r = 0; r < 4; ++r) x2r[r] = x2[row0 + ty * 4 + r];

    const int lr = t >> 3;
    const int lc = t & 7;

    for (int m0 = 0; m0 < M_CODES; m0 += 64) {
        __syncthreads();
        if (t < 64) e2s[t] = e2[m0 + t];

        float acc[4][4];
#pragma unroll
        for (int r = 0; r < 4; ++r)
#pragma unroll
            for (int c = 0; c < 4; ++c) acc[r][c] = 0.f;

        for (int k0 = 0; k0 < D_DIM; k0 += 32) {
            __syncthreads();
#pragma unroll
            for (int p = 0; p < 2; ++p) {
                int r = p * 32 + lr;
                float4 v = *(const float4*)(x + (size_t)(row0 + r) * D_DIM + k0 + lc * 4);
                *(float4*)(&As[r][lc * 4]) = v;
            }
#pragma unroll
            for (int p = 0; p < 2; ++p) {
                int r = p * 32 + lr;
                float4 v = *(const float4*)(emb + (size_t)(m0 + r) * D_DIM + k0 + lc * 4);
                Bs[lc * 4 + 0][r] = v.x;
                Bs[lc * 4 + 1][r] = v.y;
                Bs[lc * 4 + 2][r] = v.z;
                Bs[lc * 4 + 3][r] = v.w;
            }
            __syncthreads();

#pragma unroll
            for (int kk = 0; kk < 32; kk += 4) {
                float av[4][4], bv[4][4];
#pragma unroll
                for (int r = 0; r < 4; ++r) {
                    float4 a4 = *(const float4*)(&As[ty * 4 + r][kk]);
                    av[r][0] = a4.x; av[r][1] = a4.y; av[r][2] = a4.z; av[r][3] = a4.w;
                }
#pragma unroll
                for (int j = 0; j < 4; ++j) {
                    float4 b4 = *(const float4*)(&Bs[kk + j][tx * 4]);
                    bv[j][0] = b4.x; bv[j][1] = b4.y; bv[j][2] = b4.z; bv[j][3] = b4.w;
                }
#pragma unroll
                for (int j = 0; j < 4; ++j)
#pragma unroll
                    for (int r = 0; r < 4; ++r)
#pragma unroll
                        for (int c = 0; c < 4; ++c)
                            acc[r][c] += av[r][j] * bv[j][c];
            }
        }

#pragma unroll
        for (int c = 0; c < 4; ++c) {
            int mm = tx * 4 + c;
            int m  = m0 + mm;
            float e2v = e2s[mm];
#pragma unroll
            for (int r = 0; r < 4; ++r) {
                float t1 = x2r[r] + e2v;
                float dd  = t1 - 2.0f * acc[r][c];
                if (dd < rmin[r]) { rmin[r] = dd; ridx[r] = m; }
            }
        }
    }

    __syncthreads();
#pragma unroll
    for (int r = 0; r < 4; ++r) {
        redD[ty * 4 + r][tx] = rmin[r];
        redI[ty * 4 + r][tx] = ridx[r];
    }
    __syncthreads();
    if (t < 64) {
        float best = redD[t][0];
        int   bi   = redI[t][0];
#pragma unroll
        for (int i = 1; i < 16; ++i) {
            float dd = redD[t][i];
            int   ii = redI[t][i];
            if (dd < best || (dd == best && ii < bi)) { best = dd; bi = ii; }
        }
        idx_out[row0 + t]  = bi;
        idxf_out[row0 + t] = (float)bi;
    }
}

// ---------------- histogram (fallback path only) ----------------
__global__ __launch_bounds__(256) void hist_kernel(const int* __restrict__ idx,
                                                   float* __restrict__ counts) {
    int r = blockIdx.x * 256 + threadIdx.x;
    atomicAdd(&counts[idx[r]], 1.0f);
}

// ---------------- quant_st + SSE (streaming, no atomic scatter) ----------------
__global__ __launch_bounds__(256) void qst_sse_kernel(const float* __restrict__ x,
                                                      const float* __restrict__ emb,
                                                      const int* __restrict__ idx,
                                                      float* __restrict__ sse,
                                                      float* __restrict__ qst) {
    const int w    = threadIdx.x >> 6;
    const int lane = threadIdx.x & 63;
    const int rowbase = blockIdx.x * 16 + w * 4;
    float loss = 0.f;
    for (int i = 0; i < 4; ++i) {
        const int row = rowbase + i;
        const int m   = idx[row];
#pragma unroll
        for (int j = 0; j < 2; ++j) {
            const int off = j * 256 + lane * 4;
            float4 xv = *(const float4*)(x + (size_t)row * D_DIM + off);
            float4 qv = *(const float4*)(emb + (size_t)m * D_DIM + off);
            float4 qs;
            qs.x = xv.x + (qv.x - xv.x);
            qs.y = xv.y + (qv.y - xv.y);
            qs.z = xv.z + (qv.z - xv.z);
            qs.w = xv.w + (qv.w - xv.w);
            *(float4*)(qst + (size_t)row * D_DIM + off) = qs;
            float dx;
            dx = xv.x - qv.x; loss += dx * dx;
            dx = xv.y - qv.y; loss += dx * dx;
            dx = xv.z - qv.z; loss += dx * dx;
            dx = xv.w - qv.w; loss += dx * dx;
        }
    }
#pragma unroll
    for (int o = 32; o > 0; o >>= 1) loss += __shfl_xor(loss, o, 64);
    if (lane == 0) atomicAdd(sse, loss);
}

// ---------------- EMA count + Laplace normalize ----------------
__global__ __launch_bounds__(256) void f1_kernel(const float* __restrict__ ema_count,
                                                 const float* __restrict__ counts,
                                                 float* __restrict__ out_newcount,
                                                 float* __restrict__ nc_ws) {
    __shared__ float red[256];
    int t = threadIdx.x;
    float raw[8];
    float part = 0.f;
#pragma unroll
    for (int i = 0; i < 8; ++i) {
        int m = t * 8 + i;
        raw[i] = 0.999f * ema_count[m] + 0.001f * counts[m];
        part += raw[i];
    }
    red[t] = part;
    __syncthreads();
    for (int s = 128; s > 0; s >>= 1) {
        if (t < s) red[t] += red[t + s];
        __syncthreads();
    }
    float n = red[0];
    float denom = n + (float)M_CODES * 1e-5f;
#pragma unroll
    for (int i = 0; i < 8; ++i) {
        int m = t * 8 + i;
        float v = (raw[i] + 1e-5f) / denom * n;
        out_newcount[m] = v;
        nc_ws[m] = v;
    }
}

// ---------------- exclusive prefix of counts -> offs ----------------
__global__ __launch_bounds__(256) void scan_kernel(const float* __restrict__ counts,
                                                   int* __restrict__ offs) {
    __shared__ int pre[257];
    int t = threadIdx.x;
    int c[8];
    int s = 0;
#pragma unroll
    for (int i = 0; i < 8; ++i) { c[i] = (int)counts[t * 8 + i]; s += c[i]; }
    pre[t] = s;
    __syncthreads();
    if (t == 0) {
        int run = 0;
        for (int i = 0; i < 256; ++i) { int v = pre[i]; pre[i] = run; run += v; }
        pre[256] = run;
    }
    __syncthreads();
    int base = pre[t];
#pragma unroll
    for (int i = 0; i < 8; ++i) { offs[t * 8 + i] = base; base += c[i]; }
}

// ---------------- fill per-code row lists ----------------
__global__ __launch_bounds__(256) void fill_kernel(const int* __restrict__ idx,
                                                   const int* __restrict__ offs,
                                                   int* __restrict__ cursor,
                                                   int* __restrict__ order) {
    int r = blockIdx.x * 256 + threadIdx.x;
    int m = idx[r];
    int pos = atomicAdd(&cursor[m], 1);
    order[offs[m] + pos] = r;
}

// ---------------- gather-reduce dw + EMA weight + new embedding ----------------
__global__ __launch_bounds__(256) void gather_nw_kernel(const float* __restrict__ x,
                                                        const float* __restrict__ ema_weight,
                                                        const float* __restrict__ ncn,
                                                        const float* __restrict__ counts,
                                                        const int* __restrict__ offs,
                                                        const int* __restrict__ order,
                                                        float* __restrict__ out_ne,
                                                        float* __restrict__ out_nw) {
    const int m = blockIdx.x;
    const int t = threadIdx.x;
    const int beg = offs[m];
    const int end = beg + (int)counts[m];
    float ax = 0.f, ay = 0.f;
    for (int j = beg; j < end; ++j) {
        int r = order[j];
        float2 v = *(const float2*)(x + (size_t)r * D_DIM + t * 2);
        ax += v.x; ay += v.y;
    }
    size_t i = (size_t)m * D_DIM + t * 2;
    float2 wv = *(const float2*)(ema_weight + i);
    float  c  = ncn[m];
    float2 nw, ne;
    nw.x = 0.999f * wv.x + 0.001f * ax; ne.x = nw.x / c;
    nw.y = 0.999f * wv.y + 0.001f * ay; ne.y = nw.y / c;
    *(float2*)(out_nw + i) = nw;
    *(float2*)(out_ne + i) = ne;
}

// ---------------- stable compaction (used-first), normalize rows ----------------
__global__ __launch_bounds__(256) void g1_kernel(const float* __restrict__ counts,
                                                 const float* __restrict__ new_emb,
                                                 int* __restrict__ sel,
                                                 float* __restrict__ valid,
                                                 float* __restrict__ n_valid,
                                                 float* __restrict__ normed,
                                                 float* __restrict__ normedT) {
    __shared__ int pre[257];
    int t = threadIdx.x;
    int u = 0;
#pragma unroll
    for (int i = 0; i < 8; ++i) u += (counts[t * 8 + i] > 0.f) ? 1 : 0;
    pre[t] = u;
    __syncthreads();
    if (t == 0) {
        int run = 0;
        for (int i = 0; i < 256; ++i) { int c = pre[i]; pre[i] = run; run += c; }
        pre[256] = run;
    }
    __syncthreads();
    int U = pre[256];
    int base = pre[t];
    int run = 0;
    for (int i = 0; i < 8; ++i) {
        int m = t * 8 + i;
        bool used = counts[m] > 0.f;
        int ur = base + run;
        if (used) {
            if (ur < 128) sel[ur] = m;
            run++;
        } else {
            int pos = U + (m - ur);
            if (pos < 128) sel[pos] = m;
        }
    }
    __syncthreads();
    if (t < 128) valid[t] = (counts[sel[t]] > 0.f) ? 1.f : 0.f;
    __syncthreads();
    if (t == 0) {
        float s = 0.f;
        for (int i = 0; i < 128; ++i) s += valid[i];
        *n_valid = s;
    }
    int w = t >> 6, lane = t & 63;
    for (int r = w; r < 128; r += 4) {
        int sm = sel[r];
        const float* src = new_emb + (size_t)sm * D_DIM;
        float4 a = *(const float4*)(src + lane * 4);
        float4 b = *(const float4*)(src + 256 + lane * 4);
        float s = a.x*a.x + a.y*a.y + a.z*a.z + a.w*a.w
                + b.x*b.x + b.y*b.y + b.z*b.z + b.w*b.w;
#pragma unroll
        for (int o = 32; o > 0; o >>= 1) s += __shfl_xor(s, o, 64);
        float norm = fmaxf(sqrtf(s), 1e-12f);
        float vv = valid[r];
        float4 na, nb;
        na.x = a.x / norm * vv; na.y = a.y / norm * vv;
        na.z = a.z / norm * vv; na.w = a.w / norm * vv;
        nb.x = b.x / norm * vv; nb.y = b.y / norm * vv;
        nb.z = b.z / norm * vv; nb.w = b.w / norm * vv;
        *(float4*)(normed + (size_t)r * D_DIM + lane * 4) = na;
        *(float4*)(normed + (size_t)r * D_DIM + 256 + lane * 4) = nb;
        normedT[(lane * 4 + 0) * 128 + r] = na.x;
        normedT[(lane * 4 + 1) * 128 + r] = na.y;
        normedT[(lane * 4 + 2) * 128 + r] = na.z;
        normedT[(lane * 4 + 3) * 128 + r] = na.w;
        normedT[(256 + lane * 4 + 0) * 128 + r] = nb.x;
        normedT[(256 + lane * 4 + 1) * 128 + r] = nb.y;
        normedT[(256 + lane * 4 + 2) * 128 + r] = nb.z;
        normedT[(256 + lane * 4 + 3) * 128 + r] = nb.w;
    }
}

// ---------------- cosine-sim loss accumulation ----------------
__global__ __launch_bounds__(128) void g2_kernel(const float* __restrict__ normed,
                                                 const float* __restrict__ normedT,
                                                 const float* __restrict__ valid,
                                                 float* __restrict__ ortho_acc) {
    __shared__ float rowi[512];
    __shared__ float red[128];
    int i = blockIdx.x, t = threadIdx.x;
    *(float4*)(rowi + t * 4) = *(const float4*)(normed + (size_t)i * D_DIM + t * 4);
    __syncthreads();
    float dot = 0.f;
    for (int k = 0; k < D_DIM; ++k) dot += rowi[k] * normedT[k * 128 + t];
    float diag = (i == t) ? valid[i] : 0.f;
    float d = dot - diag;
    red[t] = d * d;
    __syncthreads();
    for (int s = 64; s > 0; s >>= 1) {
        if (t < s) red[t] += red[t + s];
        __syncthreads();
    }
    if (t == 0) atomicAdd(ortho_acc, red[0]);
}

// ---------------- final scalars ----------------
__global__ void g3_kernel(const float* __restrict__ sse,
                          const float* __restrict__ ortho_acc,
                          const float* __restrict__ n_valid,
                          float* __restrict__ out3) {
    if (threadIdx.x == 0 && blockIdx.x == 0) {
        float m = *sse / 16777216.f;
        out3[0] = 0.25f * m;
        out3[1] = m;
        float nv = *n_valid;
        out3[2] = *ortho_acc / (nv * nv) * 10.f;
    }
}

extern "C" void kernel_launch(void* const* d_in, const int* in_sizes, int n_in,
                              void* d_out, int out_size, void* d_ws, size_t ws_size,
                              hipStream_t stream) {
    const float* x          = (const float*)d_in[0];
    const float* emb        = (const float*)d_in[1];
    const float* ema_count  = (const float*)d_in[2];
    const float* ema_weight = (const float*)d_in[3];
    float* out = (float*)d_out;
    float* ws  = (float*)d_ws;

    float* counts  = ws + WS_COUNTS;
    int*   cursor  = (int*)(ws + WS_CURSOR);
    float* sse     = ws + WS_SSE;
    float* ortho   = ws + WS_ORTHO;
    int*   candcnt = (int*)(ws + WS_CANDCNT);
    float* e2      = ws + WS_E2;
    float* x2      = ws + WS_X2;
    int*   idxws   = (int*)(ws + WS_IDX);
    float* ncn     = ws + WS_NCN;
    int*   sel     = (int*)(ws + WS_SEL);
    float* valid   = ws + WS_VALID;
    float* nvalid  = ws + WS_NVALID;
    float* normed  = ws + WS_NORMED;
    float* normedT = ws + WS_NORMEDT;
    int*   offs    = (int*)(ws + WS_OFFS);
    int*   order   = (int*)(ws + WS_ORDER);
    int*   candC   = (int*)(ws + WS_CANDC);
    float* candD   = ws + WS_CANDD;
    unsigned short* xh = (unsigned short*)(ws + WS_XH);
    unsigned short* eh = (unsigned short*)(ws + WS_EH);

    const bool big_ws = ws_size >= (size_t)WS_TOTAL_FLOATS * sizeof(float);

    hipMemsetAsync(ws, 0, (size_t)WS_ZERO_FLOATS * sizeof(float), stream);

    if (big_ws) {
        prep_kernel<<<(M_CODES + N_ROWS) / 4, 256, 0, stream>>>(emb, x, e2, x2, xh, eh);
        approx3_kernel<<<1024, 256, 0, stream>>>(xh, eh, e2, candcnt, candC, candD);
        rerank_kernel<<<N_ROWS / 4, 256, 0, stream>>>(x, emb, e2, x2, candcnt, candC, candD,
                                                      counts, idxws, out + OUT_INDICES);
    } else {
        sq_kernel<<<(M_CODES + N_ROWS) / 4, 256, 0, stream>>>(emb, x, e2, x2);
        argmin_kernel<<<N_ROWS / 64, 256, 0, stream>>>(x, emb, e2, x2, idxws,
                                                       out + OUT_INDICES);
        hist_kernel<<<N_ROWS / 256, 256, 0, stream>>>(idxws, counts);
    }

    qst_sse_kernel<<<N_ROWS / 16, 256, 0, stream>>>(x, emb, idxws, sse, out + OUT_QST);

    f1_kernel<<<1, 256, 0, stream>>>(ema_count, counts, out + OUT_NEWCOUNT, ncn);

    scan_kernel<<<1, 256, 0, stream>>>(counts, offs);

    fill_kernel<<<N_ROWS / 256, 256, 0, stream>>>(idxws, offs, cursor, order);

    gather_nw_kernel<<<M_CODES, 256, 0, stream>>>(x, ema_weight, ncn, counts, offs, order,
                                                  out + OUT_NEWEMB, out + OUT_NEWW);

    g1_kernel<<<1, 256, 0, stream>>>(counts, out + OUT_NEWEMB, sel, valid, nvalid,
                                     normed, normedT);

    g2_kernel<<<128, 128, 0, stream>>>(normed, normedT, valid, ortho);

    g3_kernel<<<1, 64, 0, stream>>>(sse, ortho, nvalid, out + OUT_COMMIT);
}

// Round 4
// 543.729 us; speedup vs baseline: 1.2658x; 1.1975x over previous
//
#include <hip/hip_runtime.h>
#include <math.h>

#define N_ROWS 32768
#define M_CODES 2048
#define D_DIM 512
#define MARGIN 1.2e-3f
#define CAND_CAP 32

// d_out flat offsets (floats), reference return order
#define OUT_QST       0
#define OUT_COMMIT    16777216
#define OUT_CODEBOOK  16777217
#define OUT_ORTHO     16777218
#define OUT_INDICES   16777219
#define OUT_NEWEMB    16809987
#define OUT_NEWCOUNT  17858563
#define OUT_NEWW      17860611

// ---------------- workspace layout (float offsets) ----------------
// zeroed region: [0, WS_ZERO_FLOATS)
#define WS_COUNTS     0            // 2048 floats
#define WS_CURSOR     2048         // 2048 ints
#define WS_SSE        4096         // 1
#define WS_ORTHO      4097         // 1 (+6 pad)
#define WS_CANDCNT    4104         // 32768 ints
#define WS_ZERO_FLOATS 36872
#define WS_E2         36872        // 2048
#define WS_X2         38920        // 32768
#define WS_IDX        71688        // 32768 (int)
#define WS_NCN        104456       // 2048
#define WS_SEL        106504       // 128 (int)
#define WS_VALID      106632       // 128
#define WS_NVALID     106760       // 1 (+7 pad)
#define WS_NORMED     106768       // 65536
#define WS_NORMEDT    172304       // 65536
#define WS_OFFS       237840       // 2048 ints (+8 pad)
#define WS_ORDER      239896       // 32768 ints
#define WS_CANDC      272664       // 32768*32 ints
#define WS_CANDD      1321240      // 32768*32 floats
#define WS_XH         2369816      // 32768*512 shorts (8388608 float slots)
#define WS_EH         10758424     // 2048*512 shorts (524288 float slots)
#define WS_TOTAL_FLOATS 11282712

typedef __attribute__((ext_vector_type(8))) short short8v;
typedef __attribute__((ext_vector_type(4))) float f32x4;

__device__ __forceinline__ unsigned short f2bf(float f) {
    unsigned u = __float_as_uint(f);
    unsigned r = (u + 0x7fffu + ((u >> 16) & 1u)) >> 16;
    return (unsigned short)r;
}
__device__ __forceinline__ int fkey(float f) {
    int b = __float_as_int(f);
    return b >= 0 ? b : (b ^ 0x7fffffff);
}
__device__ __forceinline__ float kinv(int k) {
    int b = k >= 0 ? k : (k ^ 0x7fffffff);
    return __int_as_float(b);
}

#define GLOAD16(g, s) __builtin_amdgcn_global_load_lds( \
    (const __attribute__((address_space(1))) void*)(g), \
    (__attribute__((address_space(3))) void*)(s), 16, 0, 0)

// ---------------- prep: e2/x2 + bf16 (single, round-to-nearest) ----------------
__global__ __launch_bounds__(256) void prep_kernel(const float* __restrict__ emb,
                                                   const float* __restrict__ x,
                                                   float* __restrict__ e2,
                                                   float* __restrict__ x2,
                                                   unsigned short* __restrict__ xh,
                                                   unsigned short* __restrict__ eh) {
    int row  = blockIdx.x * 4 + (threadIdx.x >> 6);
    int lane = threadIdx.x & 63;
    bool is_e = row < M_CODES;
    const float* src = is_e ? (emb + (size_t)row * D_DIM)
                            : (x + (size_t)(row - M_CODES) * D_DIM);
    unsigned short* dh = is_e ? (eh + (size_t)row * D_DIM)
                              : (xh + (size_t)(row - M_CODES) * D_DIM);
    float4 a = *(const float4*)(src + lane * 4);
    float4 b = *(const float4*)(src + 256 + lane * 4);
    float s = a.x*a.x + a.y*a.y + a.z*a.z + a.w*a.w
            + b.x*b.x + b.y*b.y + b.z*b.z + b.w*b.w;
#pragma unroll
    for (int o = 32; o > 0; o >>= 1) s += __shfl_xor(s, o, 64);

    ushort4 h0, h1;
    h0.x = f2bf(a.x); h0.y = f2bf(a.y); h0.z = f2bf(a.z); h0.w = f2bf(a.w);
    h1.x = f2bf(b.x); h1.y = f2bf(b.y); h1.z = f2bf(b.z); h1.w = f2bf(b.w);
    *(ushort4*)(dh + lane * 4)       = h0;
    *(ushort4*)(dh + 256 + lane * 4) = h1;

    if (lane == 0) {
        if (is_e) e2[row] = s;
        else      x2[row - M_CODES] = s;
    }
}

// ---------------- sq only (fallback path) ----------------
__global__ __launch_bounds__(256) void sq_kernel(const float* __restrict__ emb,
                                                 const float* __restrict__ x,
                                                 float* __restrict__ e2,
                                                 float* __restrict__ x2) {
    int row  = blockIdx.x * 4 + (threadIdx.x >> 6);
    int lane = threadIdx.x & 63;
    const float* src = (row < M_CODES) ? (emb + (size_t)row * D_DIM)
                                       : (x + (size_t)(row - M_CODES) * D_DIM);
    float4 a = *(const float4*)(src + lane * 4);
    float4 b = *(const float4*)(src + 256 + lane * 4);
    float s = a.x*a.x + a.y*a.y + a.z*a.z + a.w*a.w
            + b.x*b.x + b.y*b.y + b.z*b.z + b.w*b.w;
#pragma unroll
    for (int o = 32; o > 0; o >>= 1) s += __shfl_xor(s, o, 64);
    if (lane == 0) {
        if (row < M_CODES) e2[row] = s;
        else               x2[row - M_CODES] = s;
    }
}

// ---------------- MFMA bf16 approx distances, 256x256 2-phase ----------------
// T3 minimum-2-phase recipe at 256^2 tile (cross-verified regime): BM=BN=256,
// BK=64, 8 waves (2x4), dbuf 128 KB LDS, one __syncthreads per K-step:
//   STAGE(buf^1, kt+1) -> compute(buf) -> barrier -> swap.
// Per wave per step: 64 MFMAs (~310 cyc) to amortize the barrier drain.
// Epilogue once per block: cross-wave row-min via LDS atomicMin (round-1's
// verified scheme), then margin-append vs block-local min (superset of the
// global-margin set: the block containing the argmin always emits it).
__global__ __launch_bounds__(512) void approx4_kernel(const unsigned short* __restrict__ xh,
                                                      const unsigned short* __restrict__ eh,
                                                      const float* __restrict__ e2g,
                                                      int* __restrict__ candcnt,
                                                      int* __restrict__ candC,
                                                      float* __restrict__ candD) {
    __shared__ short Ah[2][16384], Bh[2][16384];   // 2 x (256 rows x 64 bf16) each
    __shared__ int rowminI[256];

    const int t  = threadIdx.x;          // 0..511
    const int w  = t >> 6;               // wave 0..7
    const int l  = t & 63;
    const int ml = l & 15;
    const int q  = l >> 4;
    const int wm = w >> 2;               // row half 0..1 (128 rows)
    const int wn = w & 3;                // col quarter 0..3 (64 codes)

    const int row0  = (blockIdx.x >> 3) * 256;
    const int code0 = (blockIdx.x & 7) * 256;     // code-tile in low bits -> XCD-L2 hot

    if (t < 256) rowminI[t] = 0x7fffffff;

    // staging: thread t stages 4 pieces per matrix; row r = i*64 + (t>>3);
    // LDS piece (t&7) holds global piece (t&7)^(r&7) (row-XOR swizzle)
    const int srow = t >> 3;             // 0..63
    const int pg8  = ((t & 7) ^ (srow & 7)) * 8;

#define STAGE4(buf, ktv) do {                                                     \
    _Pragma("unroll")                                                             \
    for (int i_ = 0; i_ < 4; ++i_) {                                              \
        GLOAD16(xh + (size_t)(row0 + i_ * 64 + srow) * D_DIM + (ktv) * 64 + pg8,  \
                &Ah[(buf)][i_ * 4096 + t * 8]);                                   \
        GLOAD16(eh + (size_t)(code0 + i_ * 64 + srow) * D_DIM + (ktv) * 64 + pg8, \
                &Bh[(buf)][i_ * 4096 + t * 8]);                                   \
    }                                                                             \
} while (0)

    f32x4 acc[8][4];
#pragma unroll
    for (int mi = 0; mi < 8; ++mi)
#pragma unroll
        for (int ni = 0; ni < 4; ++ni) acc[mi][ni] = (f32x4)0.f;

    // prologue
    STAGE4(0, 0);
    __syncthreads();
    int cur = 0;

    for (int kt = 0; kt < 8; ++kt) {
        if (kt < 7) STAGE4(cur ^ 1, kt + 1);

        const short* Ab = &Ah[cur][0];
        const short* Bb = &Bh[cur][0];
#pragma unroll
        for (int kk = 0; kk < 64; kk += 32) {
            const int pb = kk >> 3;      // 0 or 4
            short8v a[8];
#pragma unroll
            for (int mi = 0; mi < 8; ++mi) {
                int m = wm * 128 + mi * 16 + ml;
                a[mi] = *(const short8v*)(Ab + m * 64 + (((pb + q) ^ (m & 7)) << 3));
            }
#pragma unroll
            for (int ni = 0; ni < 4; ++ni) {
                int n = wn * 64 + ni * 16 + ml;
                short8v b = *(const short8v*)(Bb + n * 64 + (((pb + q) ^ (n & 7)) << 3));
#pragma unroll
                for (int mi = 0; mi < 8; ++mi)
                    acc[mi][ni] = __builtin_amdgcn_mfma_f32_16x16x32_bf16(a[mi], b, acc[mi][ni], 0, 0, 0);
            }
        }

        if (kt < 7) { __syncthreads(); cur ^= 1; }
    }
#undef STAGE4

    // epilogue: d = e2 - 2*acc; block-wide per-row min; margin appends
    float e2v[4];
#pragma unroll
    for (int ni = 0; ni < 4; ++ni) e2v[ni] = e2g[code0 + wn * 64 + ni * 16 + ml];

#pragma unroll
    for (int mi = 0; mi < 8; ++mi)
#pragma unroll
        for (int r = 0; r < 4; ++r) {
            float v = 3.0e38f;
#pragma unroll
            for (int ni = 0; ni < 4; ++ni)
                v = fminf(v, e2v[ni] - 2.0f * acc[mi][ni][r]);
#pragma unroll
            for (int o = 1; o < 16; o <<= 1) v = fminf(v, __shfl_xor(v, o, 64));
            if (ml == 0) atomicMin(&rowminI[wm * 128 + mi * 16 + q * 4 + r], fkey(v));
        }
    __syncthreads();

#pragma unroll
    for (int mi = 0; mi < 8; ++mi)
#pragma unroll
        for (int r = 0; r < 4; ++r) {
            const int row_l = wm * 128 + mi * 16 + q * 4 + r;
            const float rm = kinv(rowminI[row_l]) + MARGIN;
            const int row_g = row0 + row_l;
#pragma unroll
            for (int ni = 0; ni < 4; ++ni) {
                float dd = e2v[ni] - 2.0f * acc[mi][ni][r];
                if (dd <= rm) {
                    int pos = atomicAdd(&candcnt[row_g], 1);
                    if (pos < CAND_CAP) {
                        candC[row_g * CAND_CAP + pos] = code0 + wn * 64 + ni * 16 + ml;
                        candD[row_g * CAND_CAP + pos] = dd;
                    }
                }
            }
        }
}

// ---------------- exact re-rank + histogram ----------------
__global__ __launch_bounds__(256) void rerank_kernel(const float* __restrict__ x,
                                                     const float* __restrict__ emb,
                                                     const float* __restrict__ e2,
                                                     const float* __restrict__ x2,
                                                     const int* __restrict__ candcnt,
                                                     const int* __restrict__ candC,
                                                     const float* __restrict__ candD,
                                                     float* __restrict__ counts,
                                                     int* __restrict__ idx_out,
                                                     float* __restrict__ idxf_out) {
    const int w = threadIdx.x >> 6;
    const int lane = threadIdx.x & 63;
    const int row = blockIdx.x * 4 + w;

    int cnt = candcnt[row];
    int best_c;

    if (cnt > CAND_CAP) {
        // overflow safety net (rare): exact scan of all codes (lanes parallel over codes)
        const float x2r = x2[row];
        const float* xr = x + (size_t)row * D_DIM;
        float bd = 3.0e38f;
        int   bc = 0x7fffffff;
        for (int c = lane; c < M_CODES; c += 64) {
            const float* er = emb + (size_t)c * D_DIM;
            float dot = 0.f;
            for (int k = 0; k < D_DIM; ++k) dot = fmaf(xr[k], er[k], dot);
            float d = (x2r + e2[c]) - 2.0f * dot;
            if (d < bd || (d == bd && c < bc)) { bd = d; bc = c; }
        }
#pragma unroll
        for (int o = 32; o > 0; o >>= 1) {
            float od = __shfl_xor(bd, o, 64);
            int   oc = __shfl_xor(bc, o, 64);
            if (od < bd || (od == bd && oc < bc)) { bd = od; bc = oc; }
        }
        best_c = bc;
    } else {
        float d = 3.0e38f;
        int   c = 0x7fffffff;
        if (lane < cnt) {
            d = candD[row * CAND_CAP + lane];
            c = candC[row * CAND_CAP + lane];
        }
        float dmin = d;
#pragma unroll
        for (int o = 32; o > 0; o >>= 1) dmin = fminf(dmin, __shfl_xor(dmin, o, 64));

        bool surv = (lane < cnt) && (d <= dmin + MARGIN);
        unsigned long long mask = __ballot(surv);

        if (__popcll(mask) == 1) {
            int src = __ffsll((long long)mask) - 1;
            best_c = __shfl(c, src, 64);
        } else {
            // lane-parallel exact rerank of survivors
            const float x2r = x2[row];
            const float* xr = x + (size_t)row * D_DIM;
            float4 xa = *(const float4*)(xr + lane * 8);
            float4 xb = *(const float4*)(xr + lane * 8 + 4);
            float bd = 3.0e38f;
            int   bc = 0x7fffffff;
            unsigned long long m = mask;
            while (m) {
                int src = __ffsll((long long)m) - 1;
                m &= m - 1;
                int cs = __shfl(c, src, 64);
                const float* er = emb + (size_t)cs * D_DIM;
                float4 ea = *(const float4*)(er + lane * 8);
                float4 eb = *(const float4*)(er + lane * 8 + 4);
                float dot = xa.x*ea.x + xa.y*ea.y + xa.z*ea.z + xa.w*ea.w
                          + xb.x*eb.x + xb.y*eb.y + xb.z*eb.z + xb.w*eb.w;
#pragma unroll
                for (int o = 32; o > 0; o >>= 1) dot += __shfl_xor(dot, o, 64);
                float t1 = x2r + e2[cs];
                float dex = t1 - 2.0f * dot;
                if (dex < bd || (dex == bd && cs < bc)) { bd = dex; bc = cs; }
            }
            best_c = bc;
        }
    }
    if (lane == 0) {
        idx_out[row] = best_c;
        idxf_out[row] = (float)best_c;
        atomicAdd(&counts[best_c], 1.0f);
    }
}

// ---------------- fallback fp32 argmin (round-1 kernel) ----------------
__global__ __launch_bounds__(256) void argmin_kernel(const float* __restrict__ x,
                                                     const float* __restrict__ emb,
                                                     const float* __restrict__ e2,
                                                     const float* __restrict__ x2,
                                                     int* __restrict__ idx_out,
                                                     float* __restrict__ idxf_out) {
    __shared__ float As[64][36];
    __shared__ float Bs[32][68];
    __shared__ float e2s[64];
    __shared__ float redD[64][17];
    __shared__ int   redI[64][17];

    const int t  = threadIdx.x;
    const int tx = t & 15;
    const int ty = t >> 4;
    const int row0 = blockIdx.x * 64;

    float rmin[4];
    int   ridx[4];
#pragma unroll
    for (int r = 0; r < 4; ++r) { rmin[r] = 3.0e38f; ridx[r] = 0; }

    float x2r[4];
#pragma unroll
    for (int r = 0; r < 4; ++r) x2r[r] = x2[row0 + ty * 4 + r];

    const int lr = t >> 3;
    const int lc = t & 7;

    for (int m0 = 0; m0 < M_CODES; m0 += 64) {
        __syncthreads();
        if (t < 64) e2s[t] = e2[m0 + t];

        float acc[4][4];
#pragma unroll
        for (int r = 0; r < 4; ++r)
#pragma unroll
            for (int c = 0; c < 4; ++c) acc[r][c] = 0.f;

        for (int k0 = 0; k0 < D_DIM; k0 += 32) {
            __syncthreads();
#pragma unroll
            for (int p = 0; p < 2; ++p) {
                int r = p * 32 + lr;
                float4 v = *(const float4*)(x + (size_t)(row0 + r) * D_DIM + k0 + lc * 4);
                *(float4*)(&As[r][lc * 4]) = v;
            }
#pragma unroll
            for (int p = 0; p < 2; ++p) {
                int r = p * 32 + lr;
                float4 v = *(const float4*)(emb + (size_t)(m0 + r) * D_DIM + k0 + lc * 4);
                Bs[lc * 4 + 0][r] = v.x;
                Bs[lc * 4 + 1][r] = v.y;
                Bs[lc * 4 + 2][r] = v.z;
                Bs[lc * 4 + 3][r] = v.w;
            }
            __syncthreads();

#pragma unroll
            for (int kk = 0; kk < 32; kk += 4) {
                float av[4][4], bv[4][4];
#pragma unroll
                for (int r = 0; r < 4; ++r) {
                    float4 a4 = *(const float4*)(&As[ty * 4 + r][kk]);
                    av[r][0] = a4.x; av[r][1] = a4.y; av[r][2] = a4.z; av[r][3] = a4.w;
                }
#pragma unroll
                for (int j = 0; j < 4; ++j) {
                    float4 b4 = *(const float4*)(&Bs[kk + j][tx * 4]);
                    bv[j][0] = b4.x; bv[j][1] = b4.y; bv[j][2] = b4.z; bv[j][3] = b4.w;
                }
#pragma unroll
                for (int j = 0; j < 4; ++j)
#pragma unroll
                    for (int r = 0; r < 4; ++r)
#pragma unroll
                        for (int c = 0; c < 4; ++c)
                            acc[r][c] += av[r][j] * bv[j][c];
            }
        }

#pragma unroll
        for (int c = 0; c < 4; ++c) {
            int mm = tx * 4 + c;
            int m  = m0 + mm;
            float e2v = e2s[mm];
#pragma unroll
            for (int r = 0; r < 4; ++r) {
                float t1 = x2r[r] + e2v;
                float dd  = t1 - 2.0f * acc[r][c];
                if (dd < rmin[r]) { rmin[r] = dd; ridx[r] = m; }
            }
        }
    }

    __syncthreads();
#pragma unroll
    for (int r = 0; r < 4; ++r) {
        redD[ty * 4 + r][tx] = rmin[r];
        redI[ty * 4 + r][tx] = ridx[r];
    }
    __syncthreads();
    if (t < 64) {
        float best = redD[t][0];
        int   bi   = redI[t][0];
#pragma unroll
        for (int i = 1; i < 16; ++i) {
            float dd = redD[t][i];
            int   ii = redI[t][i];
            if (dd < best || (dd == best && ii < bi)) { best = dd; bi = ii; }
        }
        idx_out[row0 + t]  = bi;
        idxf_out[row0 + t] = (float)bi;
    }
}

// ---------------- histogram (fallback path only) ----------------
__global__ __launch_bounds__(256) void hist_kernel(const int* __restrict__ idx,
                                                   float* __restrict__ counts) {
    int r = blockIdx.x * 256 + threadIdx.x;
    atomicAdd(&counts[idx[r]], 1.0f);
}

// ---------------- quant_st + SSE (streaming, no atomic scatter) ----------------
__global__ __launch_bounds__(256) void qst_sse_kernel(const float* __restrict__ x,
                                                      const float* __restrict__ emb,
                                                      const int* __restrict__ idx,
                                                      float* __restrict__ sse,
                                                      float* __restrict__ qst) {
    const int w    = threadIdx.x >> 6;
    const int lane = threadIdx.x & 63;
    const int rowbase = blockIdx.x * 16 + w * 4;
    float loss = 0.f;
    for (int i = 0; i < 4; ++i) {
        const int row = rowbase + i;
        const int m   = idx[row];
#pragma unroll
        for (int j = 0; j < 2; ++j) {
            const int off = j * 256 + lane * 4;
            float4 xv = *(const float4*)(x + (size_t)row * D_DIM + off);
            float4 qv = *(const float4*)(emb + (size_t)m * D_DIM + off);
            float4 qs;
            qs.x = xv.x + (qv.x - xv.x);
            qs.y = xv.y + (qv.y - xv.y);
            qs.z = xv.z + (qv.z - xv.z);
            qs.w = xv.w + (qv.w - xv.w);
            *(float4*)(qst + (size_t)row * D_DIM + off) = qs;
            float dx;
            dx = xv.x - qv.x; loss += dx * dx;
            dx = xv.y - qv.y; loss += dx * dx;
            dx = xv.z - qv.z; loss += dx * dx;
            dx = xv.w - qv.w; loss += dx * dx;
        }
    }
#pragma unroll
    for (int o = 32; o > 0; o >>= 1) loss += __shfl_xor(loss, o, 64);
    if (lane == 0) atomicAdd(sse, loss);
}

// ---------------- EMA count + Laplace normalize ----------------
__global__ __launch_bounds__(256) void f1_kernel(const float* __restrict__ ema_count,
                                                 const float* __restrict__ counts,
                                                 float* __restrict__ out_newcount,
                                                 float* __restrict__ nc_ws) {
    __shared__ float red[256];
    int t = threadIdx.x;
    float raw[8];
    float part = 0.f;
#pragma unroll
    for (int i = 0; i < 8; ++i) {
        int m = t * 8 + i;
        raw[i] = 0.999f * ema_count[m] + 0.001f * counts[m];
        part += raw[i];
    }
    red[t] = part;
    __syncthreads();
    for (int s = 128; s > 0; s >>= 1) {
        if (t < s) red[t] += red[t + s];
        __syncthreads();
    }
    float n = red[0];
    float denom = n + (float)M_CODES * 1e-5f;
#pragma unroll
    for (int i = 0; i < 8; ++i) {
        int m = t * 8 + i;
        float v = (raw[i] + 1e-5f) / denom * n;
        out_newcount[m] = v;
        nc_ws[m] = v;
    }
}

// ---------------- exclusive prefix of counts -> offs ----------------
__global__ __launch_bounds__(256) void scan_kernel(const float* __restrict__ counts,
                                                   int* __restrict__ offs) {
    __shared__ int pre[257];
    int t = threadIdx.x;
    int c[8];
    int s = 0;
#pragma unroll
    for (int i = 0; i < 8; ++i) { c[i] = (int)counts[t * 8 + i]; s += c[i]; }
    pre[t] = s;
    __syncthreads();
    if (t == 0) {
        int run = 0;
        for (int i = 0; i < 256; ++i) { int v = pre[i]; pre[i] = run; run += v; }
        pre[256] = run;
    }
    __syncthreads();
    int base = pre[t];
#pragma unroll
    for (int i = 0; i < 8; ++i) { offs[t * 8 + i] = base; base += c[i]; }
}

// ---------------- fill per-code row lists ----------------
__global__ __launch_bounds__(256) void fill_kernel(const int* __restrict__ idx,
                                                   const int* __restrict__ offs,
                                                   int* __restrict__ cursor,
                                                   int* __restrict__ order) {
    int r = blockIdx.x * 256 + threadIdx.x;
    int m = idx[r];
    int pos = atomicAdd(&cursor[m], 1);
    order[offs[m] + pos] = r;
}

// ---------------- gather-reduce dw + EMA weight + new embedding ----------------
__global__ __launch_bounds__(256) void gather_nw_kernel(const float* __restrict__ x,
                                                        const float* __restrict__ ema_weight,
                                                        const float* __restrict__ ncn,
                                                        const float* __restrict__ counts,
                                                        const int* __restrict__ offs,
                                                        const int* __restrict__ order,
                                                        float* __restrict__ out_ne,
                                                        float* __restrict__ out_nw) {
    const int m = blockIdx.x;
    const int t = threadIdx.x;
    const int beg = offs[m];
    const int end = beg + (int)counts[m];
    float ax = 0.f, ay = 0.f;
    for (int j = beg; j < end; ++j) {
        int r = order[j];
        float2 v = *(const float2*)(x + (size_t)r * D_DIM + t * 2);
        ax += v.x; ay += v.y;
    }
    size_t i = (size_t)m * D_DIM + t * 2;
    float2 wv = *(const float2*)(ema_weight + i);
    float  c  = ncn[m];
    float2 nw, ne;
    nw.x = 0.999f * wv.x + 0.001f * ax; ne.x = nw.x / c;
    nw.y = 0.999f * wv.y + 0.001f * ay; ne.y = nw.y / c;
    *(float2*)(out_nw + i) = nw;
    *(float2*)(out_ne + i) = ne;
}

// ---------------- stable compaction (used-first), normalize rows ----------------
__global__ __launch_bounds__(256) void g1_kernel(const float* __restrict__ counts,
                                                 const float* __restrict__ new_emb,
                                                 int* __restrict__ sel,
                                                 float* __restrict__ valid,
                                                 float* __restrict__ n_valid,
                                                 float* __restrict__ normed,
                                                 float* __restrict__ normedT) {
    __shared__ int pre[257];
    int t = threadIdx.x;
    int u = 0;
#pragma unroll
    for (int i = 0; i < 8; ++i) u += (counts[t * 8 + i] > 0.f) ? 1 : 0;
    pre[t] = u;
    __syncthreads();
    if (t == 0) {
        int run = 0;
        for (int i = 0; i < 256; ++i) { int c = pre[i]; pre[i] = run; run += c; }
        pre[256] = run;
    }
    __syncthreads();
    int U = pre[256];
    int base = pre[t];
    int run = 0;
    for (int i = 0; i < 8; ++i) {
        int m = t * 8 + i;
        bool used = counts[m] > 0.f;
        int ur = base + run;
        if (used) {
            if (ur < 128) sel[ur] = m;
            run++;
        } else {
            int pos = U + (m - ur);
            if (pos < 128) sel[pos] = m;
        }
    }
    __syncthreads();
    if (t < 128) valid[t] = (counts[sel[t]] > 0.f) ? 1.f : 0.f;
    __syncthreads();
    if (t == 0) {
        float s = 0.f;
        for (int i = 0; i < 128; ++i) s += valid[i];
        *n_valid = s;
    }
    int w = t >> 6, lane = t & 63;
    for (int r = w; r < 128; r += 4) {
        int sm = sel[r];
        const float* src = new_emb + (size_t)sm * D_DIM;
        float4 a = *(const float4*)(src + lane * 4);
        float4 b = *(const float4*)(src + 256 + lane * 4);
        float s = a.x*a.x + a.y*a.y + a.z*a.z + a.w*a.w
                + b.x*b.x + b.y*b.y + b.z*b.z + b.w*b.w;
#pragma unroll
        for (int o = 32; o > 0; o >>= 1) s += __shfl_xor(s, o, 64);
        float norm = fmaxf(sqrtf(s), 1e-12f);
        float vv = valid[r];
        float4 na, nb;
        na.x = a.x / norm * vv; na.y = a.y / norm * vv;
        na.z = a.z / norm * vv; na.w = a.w / norm * vv;
        nb.x = b.x / norm * vv; nb.y = b.y / norm * vv;
        nb.z = b.z / norm * vv; nb.w = b.w / norm * vv;
        *(float4*)(normed + (size_t)r * D_DIM + lane * 4) = na;
        *(float4*)(normed + (size_t)r * D_DIM + 256 + lane * 4) = nb;
        normedT[(lane * 4 + 0) * 128 + r] = na.x;
        normedT[(lane * 4 + 1) * 128 + r] = na.y;
        normedT[(lane * 4 + 2) * 128 + r] = na.z;
        normedT[(lane * 4 + 3) * 128 + r] = na.w;
        normedT[(256 + lane * 4 + 0) * 128 + r] = nb.x;
        normedT[(256 + lane * 4 + 1) * 128 + r] = nb.y;
        normedT[(256 + lane * 4 + 2) * 128 + r] = nb.z;
        normedT[(256 + lane * 4 + 3) * 128 + r] = nb.w;
    }
}

// ---------------- cosine-sim loss accumulation ----------------
__global__ __launch_bounds__(128) void g2_kernel(const float* __restrict__ normed,
                                                 const float* __restrict__ normedT,
                                                 const float* __restrict__ valid,
                                                 float* __restrict__ ortho_acc) {
    __shared__ float rowi[512];
    __shared__ float red[128];
    int i = blockIdx.x, t = threadIdx.x;
    *(float4*)(rowi + t * 4) = *(const float4*)(normed + (size_t)i * D_DIM + t * 4);
    __syncthreads();
    float dot = 0.f;
    for (int k = 0; k < D_DIM; ++k) dot += rowi[k] * normedT[k * 128 + t];
    float diag = (i == t) ? valid[i] : 0.f;
    float d = dot - diag;
    red[t] = d * d;
    __syncthreads();
    for (int s = 64; s > 0; s >>= 1) {
        if (t < s) red[t] += red[t + s];
        __syncthreads();
    }
    if (t == 0) atomicAdd(ortho_acc, red[0]);
}

// ---------------- final scalars ----------------
__global__ void g3_kernel(const float* __restrict__ sse,
                          const float* __restrict__ ortho_acc,
                          const float* __restrict__ n_valid,
                          float* __restrict__ out3) {
    if (threadIdx.x == 0 && blockIdx.x == 0) {
        float m = *sse / 16777216.f;
        out3[0] = 0.25f * m;
        out3[1] = m;
        float nv = *n_valid;
        out3[2] = *ortho_acc / (nv * nv) * 10.f;
    }
}

extern "C" void kernel_launch(void* const* d_in, const int* in_sizes, int n_in,
                              void* d_out, int out_size, void* d_ws, size_t ws_size,
                              hipStream_t stream) {
    const float* x          = (const float*)d_in[0];
    const float* emb        = (const float*)d_in[1];
    const float* ema_count  = (const float*)d_in[2];
    const float* ema_weight = (const float*)d_in[3];
    float* out = (float*)d_out;
    float* ws  = (float*)d_ws;

    float* counts  = ws + WS_COUNTS;
    int*   cursor  = (int*)(ws + WS_CURSOR);
    float* sse     = ws + WS_SSE;
    float* ortho   = ws + WS_ORTHO;
    int*   candcnt = (int*)(ws + WS_CANDCNT);
    float* e2      = ws + WS_E2;
    float* x2      = ws + WS_X2;
    int*   idxws   = (int*)(ws + WS_IDX);
    float* ncn     = ws + WS_NCN;
    int*   sel     = (int*)(ws + WS_SEL);
    float* valid   = ws + WS_VALID;
    float* nvalid  = ws + WS_NVALID;
    float* normed  = ws + WS_NORMED;
    float* normedT = ws + WS_NORMEDT;
    int*   offs    = (int*)(ws + WS_OFFS);
    int*   order   = (int*)(ws + WS_ORDER);
    int*   candC   = (int*)(ws + WS_CANDC);
    float* candD   = ws + WS_CANDD;
    unsigned short* xh = (unsigned short*)(ws + WS_XH);
    unsigned short* eh = (unsigned short*)(ws + WS_EH);

    const bool big_ws = ws_size >= (size_t)WS_TOTAL_FLOATS * sizeof(float);

    hipMemsetAsync(ws, 0, (size_t)WS_ZERO_FLOATS * sizeof(float), stream);

    if (big_ws) {
        prep_kernel<<<(M_CODES + N_ROWS) / 4, 256, 0, stream>>>(emb, x, e2, x2, xh, eh);
        approx4_kernel<<<1024, 512, 0, stream>>>(xh, eh, e2, candcnt, candC, candD);
        rerank_kernel<<<N_ROWS / 4, 256, 0, stream>>>(x, emb, e2, x2, candcnt, candC, candD,
                                                      counts, idxws, out + OUT_INDICES);
    } else {
        sq_kernel<<<(M_CODES + N_ROWS) / 4, 256, 0, stream>>>(emb, x, e2, x2);
        argmin_kernel<<<N_ROWS / 64, 256, 0, stream>>>(x, emb, e2, x2, idxws,
                                                       out + OUT_INDICES);
        hist_kernel<<<N_ROWS / 256, 256, 0, stream>>>(idxws, counts);
    }

    qst_sse_kernel<<<N_ROWS / 16, 256, 0, stream>>>(x, emb, idxws, sse, out + OUT_QST);

    f1_kernel<<<1, 256, 0, stream>>>(ema_count, counts, out + OUT_NEWCOUNT, ncn);

    scan_kernel<<<1, 256, 0, stream>>>(counts, offs);

    fill_kernel<<<N_ROWS / 256, 256, 0, stream>>>(idxws, offs, cursor, order);

    gather_nw_kernel<<<M_CODES, 256, 0, stream>>>(x, ema_weight, ncn, counts, offs, order,
                                                  out + OUT_NEWEMB, out + OUT_NEWW);

    g1_kernel<<<1, 256, 0, stream>>>(counts, out + OUT_NEWEMB, sel, valid, nvalid,
                                     normed, normedT);

    g2_kernel<<<128, 128, 0, stream>>>(normed, normedT, valid, ortho);

    g3_kernel<<<1, 64, 0, stream>>>(sse, ortho, nvalid, out + OUT_COMMIT);
}